// Round 6
// baseline (160.035 us; speedup 1.0000x reference)
//
#include <hip/hip_runtime.h>
#include <math.h>

#define NHID 128
#define TILE_E 128
#define LDK 264   // padded K stride in bf16 elems (fallback kernel)

typedef __bf16 bf16x8 __attribute__((ext_vector_type(8)));
typedef float f32x4 __attribute__((ext_vector_type(4)));
typedef unsigned short u16x8 __attribute__((ext_vector_type(8)));

__device__ __forceinline__ unsigned short f2bf(float f) {
  unsigned int u = __float_as_uint(f);
  u += 0x7fffu + ((u >> 16) & 1u);   // RNE
  return (unsigned short)(u >> 16);
}
__device__ __forceinline__ float bf2f(unsigned short u) {
  return __uint_as_float(((unsigned int)u) << 16);
}

// ============================================================================
// Phase 0: repack W1 (fp32 [256][128]) into fragment-ordered bf16 (64 KB).
// Slot s = ((w*16 + ks*4 + nt)*64 + lane); elem j. Wave-quadrant w=(kh,ch):
// kh = A/B half (W1 rows 0-127 / 128-255), ch = col half. One-time, ~2 us.
// Lets phase-1 blocks load their 16 MFMA B-fragments with 16 coalesced
// 16B loads instead of 128 scalar gathers + 128 f2bf per thread.
// ============================================================================
__global__ __launch_bounds__(256)
void repack_w1(const float* __restrict__ W1, unsigned short* __restrict__ Wrep)
{
  const int t    = blockIdx.x * 256 + threadIdx.x;  // 0..4095
  const int w    = t >> 10;        // quadrant 0..3
  const int f    = (t >> 6) & 15;  // fragment 0..15 (ks*4+nt)
  const int lane = t & 63;
  const int kh   = w >> 1, ch = w & 1;
  const int ks   = f >> 2, nt = f & 3;
  const int quad = lane >> 4, m15 = lane & 15;
  const int krow = kh * 128 + ks * 32 + quad * 8;
  const int col  = ch * 64 + nt * 16 + m15;

  u16x8 v;
  #pragma unroll
  for (int j = 0; j < 8; ++j)
    v[j] = f2bf(W1[(size_t)(krow + j) * NHID + col]);
  *(u16x8*)(Wrep + (size_t)t * 8) = v;
}

// ============================================================================
// Phase 1: AB[node][0:128]  = inputs[node]·W1[0:128][:]   + bias1   (A half)
//          AB[node][128:256]= inputs[node]·W1[128:256][:]           (B half)
// Barrier-free: each wave owns a col-quadrant; 16-row tiles staged in
// registers with depth-1 prefetch (next tile's loads fly under MFMA+epilogue).
// W1 fragments come from Wrep: 16 coalesced 16B loads (L2-hot), replacing the
// 128-scalar-gather prologue that was invariant across all prior variants.
// ============================================================================
__global__ __launch_bounds__(256)
void precompute_ab(const float* __restrict__ inputs,
                   const unsigned short* __restrict__ Wrep,
                   const float* __restrict__ bias1,
                   unsigned short* __restrict__ AB,
                   int n_nodes)
{
  __shared__ __align__(16) unsigned short sC[4][16][72];  // 9.2 KB wave-private repack

  const int tid  = threadIdx.x;
  const int lane = tid & 63;
  const int w    = tid >> 6;          // wave 0..3 -> (A/B half, col half)
  const int m15  = lane & 15;
  const int quad = lane >> 4;

  // ---- W1 B-fragments: 16 coalesced 16B loads from Wrep ----
  bf16x8 bw[4][4];
  #pragma unroll
  for (int ks = 0; ks < 4; ++ks)
    #pragma unroll
    for (int nt = 0; nt < 4; ++nt)
      bw[ks][nt] = __builtin_bit_cast(bf16x8,
        *(const u16x8*)(Wrep + ((size_t)((w * 16 + ks * 4 + nt) * 64 + lane)) * 8));

  // bias1 folded into the A half only (waves 0,1)
  float bias[4];
  #pragma unroll
  for (int nt = 0; nt < 4; ++nt)
    bias[nt] = (w < 2) ? bias1[(w & 1) * 64 + nt * 16 + m15] : 0.f;

  const int ntiles = (n_nodes + 15) >> 4;
  const int stride = gridDim.x;
  int t = blockIdx.x;

  // ---- prologue: load tile t's 16-row slice into regs ----
  float4 pf[8];
  {
    int r = t * 16 + m15;
    if (r >= n_nodes) r = n_nodes - 1;
    const float* rp = inputs + (size_t)r * NHID + quad * 8;
    #pragma unroll
    for (int ks = 0; ks < 4; ++ks) {
      pf[2 * ks]     = *(const float4*)(rp + ks * 32);
      pf[2 * ks + 1] = *(const float4*)(rp + ks * 32 + 4);
    }
  }

  for (; t < ntiles; t += stride) {
    // ---- convert current tile fp32 -> bf16 fragments ----
    u16x8 af[4];
    #pragma unroll
    for (int ks = 0; ks < 4; ++ks) {
      u16x8 tt;
      tt[0] = f2bf(pf[2 * ks].x);     tt[1] = f2bf(pf[2 * ks].y);
      tt[2] = f2bf(pf[2 * ks].z);     tt[3] = f2bf(pf[2 * ks].w);
      tt[4] = f2bf(pf[2 * ks + 1].x); tt[5] = f2bf(pf[2 * ks + 1].y);
      tt[6] = f2bf(pf[2 * ks + 1].z); tt[7] = f2bf(pf[2 * ks + 1].w);
      af[ks] = tt;
    }

    // ---- issue next tile's loads now; no barrier in this loop, they fly ----
    {
      int tn = t + stride;
      if (tn < ntiles) {
        int r = tn * 16 + m15;
        if (r >= n_nodes) r = n_nodes - 1;
        const float* rp = inputs + (size_t)r * NHID + quad * 8;
        #pragma unroll
        for (int ks = 0; ks < 4; ++ks) {
          pf[2 * ks]     = *(const float4*)(rp + ks * 32);
          pf[2 * ks + 1] = *(const float4*)(rp + ks * 32 + 4);
        }
      }
    }

    // ---- MFMA: 16 rows x 64 cols per wave (full K=128 over 4 steps) ----
    f32x4 acc[4];
    #pragma unroll
    for (int nt = 0; nt < 4; ++nt)
      acc[nt] = (f32x4){0.f, 0.f, 0.f, 0.f};

    #pragma unroll
    for (int ks = 0; ks < 4; ++ks) {
      bf16x8 a = __builtin_bit_cast(bf16x8, af[ks]);
      #pragma unroll
      for (int nt = 0; nt < 4; ++nt)
        acc[nt] = __builtin_amdgcn_mfma_f32_16x16x32_bf16(a, bw[ks][nt], acc[nt], 0, 0, 0);
    }

    // ---- epilogue: +bias, cvt bf16, wave-private LDS repack, 16B stores ----
    // D layout: col = lane&15 (+nt*16), row = quad*4 + r
    #pragma unroll
    for (int nt = 0; nt < 4; ++nt)
      #pragma unroll
      for (int r = 0; r < 4; ++r)
        sC[w][quad * 4 + r][nt * 16 + m15] = f2bf(acc[nt][r] + bias[nt]);

    // wave-local write->read: compiler inserts lgkmcnt waits; no barrier needed
    const int rowbase = t * 16;
    #pragma unroll
    for (int p = 0; p < 2; ++p) {
      const int row  = p * 8 + (lane >> 3);
      const int node = rowbase + row;
      if (node < n_nodes) {
        u16x8 v = *(const u16x8*)&sC[w][row][(lane & 7) * 8];
        *(u16x8*)(AB + (size_t)node * 256 + w * 64 + (lane & 7) * 8) = v;
      }
    }
  }
}

// ============================================================================
// Phase 2: out[e] = sigmoid( relu(AB[x[e]][0:128] + AB[y[e]][128:256]) · W2 + b2 )
// 16 lanes/edge, 4-edge tiles, cross-iteration ping-pong (round-5 proven).
// Unchanged this round for clean attribution.
// ============================================================================
__global__ __launch_bounds__(256, 4)
void edge_eval(const unsigned short* __restrict__ AB,
               const int* __restrict__ x_idx,
               const int* __restrict__ y_idx,
               const float* __restrict__ W2,
               const float* __restrict__ bias2,
               float* __restrict__ out,
               int n_edges)
{
  const int tid = threadIdx.x;
  const int g   = tid >> 4;   // group 0..15 within block
  const int l   = tid & 15;   // lane within group

  float w2[8];
  {
    float4 a = *(const float4*)(W2 + l * 8);
    float4 b = *(const float4*)(W2 + l * 8 + 4);
    w2[0] = a.x; w2[1] = a.y; w2[2] = a.z; w2[3] = a.w;
    w2[4] = b.x; w2[5] = b.y; w2[6] = b.z; w2[7] = b.w;
  }
  const float b2   = bias2[0];
  const int   last = n_edges - 1;
  const int   step = gridDim.x * 64;

#define LOADSET(ax, by, bs)                                              \
  _Pragma("unroll")                                                      \
  for (int k = 0; k < 4; ++k) {                                          \
    int e = (bs) + 16 * k + g;                                           \
    int c = e < last ? e : last;                                         \
    int xi = x_idx[c];                                                   \
    int yi = y_idx[c];                                                   \
    ax[k] = *(const u16x8*)(AB + (size_t)xi * 256 + l * 8);              \
    by[k] = *(const u16x8*)(AB + (size_t)yi * 256 + 128 + l * 8);        \
  }

#define COMPSET(ax, by, bs)                                              \
  {                                                                      \
    float s[4] = {0.f, 0.f, 0.f, 0.f};                                   \
    _Pragma("unroll")                                                    \
    for (int j = 0; j < 8; ++j)                                          \
      _Pragma("unroll")                                                  \
      for (int k = 0; k < 4; ++k) {                                      \
        float h = bf2f(ax[k][j]) + bf2f(by[k][j]);                       \
        h = fmaxf(h, 0.f);                                               \
        s[k] = fmaf(h, w2[j], s[k]);                                     \
      }                                                                  \
    _Pragma("unroll")                                                    \
    for (int d = 1; d < 16; d <<= 1)                                     \
      _Pragma("unroll")                                                  \
      for (int k = 0; k < 4; ++k)                                        \
        s[k] += __shfl_xor(s[k], d);                                     \
    if (l == 0) {                                                        \
      _Pragma("unroll")                                                  \
      for (int k = 0; k < 4; ++k) {                                      \
        int e = (bs) + 16 * k + g;                                       \
        if (e < n_edges)                                                 \
          out[e] = 1.f / (1.f + __expf(-(s[k] + b2)));                   \
      }                                                                  \
    }                                                                    \
  }

  u16x8 axA[4], byA[4], axB[4], byB[4];
  int base = blockIdx.x * 64;
  if (base >= n_edges) return;

  LOADSET(axA, byA, base)
  while (true) {
    int nb = base + step;
    if (nb < n_edges) LOADSET(axB, byB, nb)
    COMPSET(axA, byA, base)
    base = nb;
    if (base >= n_edges) break;

    nb = base + step;
    if (nb < n_edges) LOADSET(axA, byA, nb)
    COMPSET(axB, byB, base)
    base = nb;
    if (base >= n_edges) break;
  }
#undef LOADSET
#undef COMPSET
}

// ============================================================================
// Fallback: previous fused kernel (used only if workspace is too small)
// ============================================================================
__global__ __launch_bounds__(256, 1)
void mlp_edge_decoder(const float* __restrict__ inputs,
                      const int* __restrict__ x_idx,
                      const int* __restrict__ y_idx,
                      const float* __restrict__ W1,
                      const float* __restrict__ bias1,
                      const float* __restrict__ W2,
                      const float* __restrict__ bias2,
                      float* __restrict__ out,
                      int n_edges)
{
  __shared__ __align__(16) unsigned short sW1T[NHID][LDK];
  __shared__ __align__(16) unsigned short sA[TILE_E][LDK];
  __shared__ float sB1[NHID];
  __shared__ float sW2[NHID];
  __shared__ float sRed[2][TILE_E];

  const int tid  = threadIdx.x;
  const int lane = tid & 63;
  const int wv   = tid >> 6;
  const int seg  = tid & 63;
  const int m15  = lane & 15;
  const int quad = lane >> 4;
  const int eh   = wv >> 1;
  const int ch   = wv & 1;

  for (int i = tid; i < 256 * NHID; i += 256) {
    int k = i >> 7;
    int n = i & 127;
    sW1T[n][k] = f2bf(W1[i]);
  }
  if (tid < NHID) { sB1[tid] = bias1[tid]; sW2[tid] = W2[tid]; }
  const float b2 = bias2[0];

  const int stride = gridDim.x * TILE_E;
  int ebase = blockIdx.x * TILE_E;

  float4 stage[32];
  #pragma unroll
  for (int j = 0; j < 32; ++j) {
    int e  = ebase + 4 * j + wv;
    int ec = (e < n_edges) ? e : 0;
    int idx = (seg < 32) ? x_idx[ec] : y_idx[ec];
    stage[j] = *(const float4*)(inputs + (size_t)idx * NHID + (seg & 31) * 4);
  }

  for (; ebase < n_edges; ebase += stride) {
    #pragma unroll
    for (int j = 0; j < 32; ++j) {
      int r = wv + 4 * j;
      ushort4 p;
      p.x = f2bf(stage[j].x);
      p.y = f2bf(stage[j].y);
      p.z = f2bf(stage[j].z);
      p.w = f2bf(stage[j].w);
      *(ushort4*)(&sA[r][seg * 4]) = p;
    }
    __syncthreads();

    {
      int nb = ebase + stride;
      if (nb < n_edges) {
        #pragma unroll
        for (int j = 0; j < 32; ++j) {
          int e  = nb + 4 * j + wv;
          int ec = (e < n_edges) ? e : 0;
          int idx = (seg < 32) ? x_idx[ec] : y_idx[ec];
          stage[j] = *(const float4*)(inputs + (size_t)idx * NHID + (seg & 31) * 4);
        }
      }
    }

    f32x4 acc[4][4];
    #pragma unroll
    for (int mt = 0; mt < 4; ++mt)
      #pragma unroll
      for (int nt = 0; nt < 4; ++nt)
        acc[mt][nt] = (f32x4){0.f, 0.f, 0.f, 0.f};

    #pragma unroll
    for (int ks = 0; ks < 8; ++ks) {
      bf16x8 af[4], bfr[4];
      #pragma unroll
      for (int mt = 0; mt < 4; ++mt)
        af[mt] = __builtin_bit_cast(bf16x8,
                   *(const u16x8*)(&sA[eh * 64 + mt * 16 + m15][ks * 32 + quad * 8]));
      #pragma unroll
      for (int nt = 0; nt < 4; ++nt)
        bfr[nt] = __builtin_bit_cast(bf16x8,
                   *(const u16x8*)(&sW1T[ch * 64 + nt * 16 + m15][ks * 32 + quad * 8]));
      #pragma unroll
      for (int mt = 0; mt < 4; ++mt)
        #pragma unroll
        for (int nt = 0; nt < 4; ++nt)
          acc[mt][nt] = __builtin_amdgcn_mfma_f32_16x16x32_bf16(af[mt], bfr[nt], acc[mt][nt], 0, 0, 0);
    }

    #pragma unroll
    for (int mt = 0; mt < 4; ++mt) {
      #pragma unroll
      for (int r = 0; r < 4; ++r) {
        float s = 0.f;
        #pragma unroll
        for (int nt = 0; nt < 4; ++nt) {
          int c = ch * 64 + nt * 16 + m15;
          float h = acc[mt][nt][r] + sB1[c];
          h = fmaxf(h, 0.f);
          s = fmaf(h, sW2[c], s);
        }
        s += __shfl_xor(s, 1);
        s += __shfl_xor(s, 2);
        s += __shfl_xor(s, 4);
        s += __shfl_xor(s, 8);
        if (m15 == 0) sRed[ch][eh * 64 + mt * 16 + quad * 4 + r] = s;
      }
    }
    __syncthreads();

    if (tid < TILE_E) {
      int e = ebase + tid;
      if (e < n_edges) {
        float s = sRed[0][tid] + sRed[1][tid] + b2;
        out[e] = 1.f / (1.f + __expf(-s));
      }
    }
  }
}

extern "C" void kernel_launch(void* const* d_in, const int* in_sizes, int n_in,
                              void* d_out, int out_size, void* d_ws, size_t ws_size,
                              hipStream_t stream) {
  const float* inputs = (const float*)d_in[0];
  const int*   x_idx  = (const int*)d_in[1];
  const int*   y_idx  = (const int*)d_in[2];
  const float* W1     = (const float*)d_in[3];
  const float* bias1  = (const float*)d_in[4];
  const float* W2     = (const float*)d_in[5];
  const float* bias2  = (const float*)d_in[6];
  float* out = (float*)d_out;
  const int n_edges = in_sizes[1];
  const int n_nodes = in_sizes[0] / NHID;

  const size_t ab_bytes = (size_t)n_nodes * 256 * sizeof(unsigned short);
  const size_t need = ab_bytes + 65536;   // AB + repacked W1 fragments
  if (d_ws != nullptr && ws_size >= need) {
    unsigned short* AB   = (unsigned short*)d_ws;
    unsigned short* Wrep = (unsigned short*)((char*)d_ws + ab_bytes);

    // Phase 0: one-time W1 fragment repack (4096 threads, ~2 us)
    hipLaunchKernelGGL(repack_w1, dim3(16), dim3(256), 0, stream, W1, Wrep);

    // Phase 1: 16-row tiles, 2 tiles/block, barrier-free, trivial prologue
    const int ntiles = (n_nodes + 15) >> 4;
    int grid1 = (ntiles + 1) / 2;
    if (grid1 < 1) grid1 = 1;
    hipLaunchKernelGGL(precompute_ab, dim3(grid1), dim3(256), 0, stream,
                       inputs, Wrep, bias1, AB, n_nodes);

    // Phase 2: 64-edge tiles, ping-pong pipeline, ~4 iterations/block
    const int etiles = (n_edges + 63) / 64;
    int grid2 = (etiles + 3) / 4;
    if (grid2 < 1) grid2 = 1;
    hipLaunchKernelGGL(edge_eval, dim3(grid2), dim3(256), 0, stream,
                       AB, x_idx, y_idx, W2, bias2, out, n_edges);
  } else {
    hipLaunchKernelGGL(mlp_edge_decoder, dim3(512), dim3(256), 0, stream,
                       inputs, x_idx, y_idx, W1, bias1, W2, bias2, out, n_edges);
  }
}